// Round 9
// baseline (708.507 us; speedup 1.0000x reference)
//
#include <hip/hip_runtime.h>

#define D 128
#define NLAYERS 5

using short8  = __attribute__((ext_vector_type(8))) short;
using short4v = __attribute__((ext_vector_type(4))) short;
using floatx4 = __attribute__((ext_vector_type(4))) float;
using floatx2 = __attribute__((ext_vector_type(2))) float;

__device__ __forceinline__ unsigned bf16_rne(float x) {
    unsigned u = __float_as_uint(x);
    return (u + 0x7fffu + ((u >> 16) & 1u)) >> 16;
}
__device__ __forceinline__ float bf16_to_f32(short s) {
    return __uint_as_float(((unsigned)(unsigned short)s) << 16);
}

// H is stored as fp8 e4m3 with a fixed x16 scale (power of 2 => scaling is exact).
#define HSCALE 16.0f
#define HSCALE_INV 0.0625f

// ---------------- prepA: W transpose/bf16 + H0 gather (fp8) + fused edge histogram ----------------
__global__ void prepA_kernel(const int* __restrict__ x, const float* __restrict__ emb,
                             const float* __restrict__ Wa, const float* __restrict__ Wb,
                             const int* __restrict__ edst,
                             unsigned char* __restrict__ H0, short* __restrict__ wt,
                             int* __restrict__ deg,
                             int n_nodes, int n_edges) {
    const int gtid = blockIdx.x * 256 + threadIdx.x;
    const int gsz  = gridDim.x * 256;
    for (int g = gtid; g < 2 * NLAYERS * D * D; g += gsz) {
        int mat = g >> 14, idx = g & 16383;
        int n = idx >> 7, k = idx & 127;
        const float* W = (mat & 1) ? (Wb + (size_t)(mat >> 1) * D * D)
                                   : (Wa + (size_t)(mat >> 1) * D * D);
        wt[g] = (short)bf16_rne(W[k * D + n]);
    }
    for (int t = gtid; t < n_nodes * 32; t += gsz) {
        int node = t >> 5, lane = t & 31;
        int s = x[node];
        const float4 v = *reinterpret_cast<const float4*>(emb + (size_t)s * D + lane * 4);
        int w = __builtin_amdgcn_cvt_pk_fp8_f32(v.x * HSCALE, v.y * HSCALE, 0, false);
        w = __builtin_amdgcn_cvt_pk_fp8_f32(v.z * HSCALE, v.w * HSCALE, w, true);
        reinterpret_cast<unsigned int*>(H0)[(size_t)node * 32 + lane] = (unsigned int)w;
    }
    for (int e = gtid; e < n_edges; e += gsz) atomicAdd(&deg[edst[e]], 1);
}

#define SCAN_TILE 1024
__global__ void scan_sums_kernel(const int* __restrict__ deg, int* __restrict__ bsums, int n) {
    __shared__ int red[256];
    int base = blockIdx.x * SCAN_TILE + threadIdx.x * 4;
    int s = 0;
    #pragma unroll
    for (int j = 0; j < 4; j++) {
        int i = base + j;
        if (i < n) s += deg[i];
    }
    red[threadIdx.x] = s;
    __syncthreads();
    for (int off = 128; off > 0; off >>= 1) {
        if (threadIdx.x < off) red[threadIdx.x] += red[threadIdx.x + off];
        __syncthreads();
    }
    if (threadIdx.x == 0) bsums[blockIdx.x] = red[0];
}

__global__ void scan_bsums_kernel(int* __restrict__ bsums, int nblocks) {
    __shared__ int sdata[256];
    int carry = 0;
    for (int base = 0; base < nblocks; base += 256) {
        int i = base + threadIdx.x;
        int v = (i < nblocks) ? bsums[i] : 0;
        sdata[threadIdx.x] = v;
        __syncthreads();
        for (int off = 1; off < 256; off <<= 1) {
            int t = (threadIdx.x >= off) ? sdata[threadIdx.x - off] : 0;
            __syncthreads();
            sdata[threadIdx.x] += t;
            __syncthreads();
        }
        int incl = sdata[threadIdx.x];
        if (i < nblocks) bsums[i] = carry + incl - v;
        carry += sdata[255];
        __syncthreads();
    }
}

__global__ void scan_final_kernel(const int* __restrict__ deg, const int* __restrict__ bsums,
                                  int* __restrict__ offsets, int* __restrict__ cursor, int n) {
    __shared__ int sdata[256];
    int base = blockIdx.x * SCAN_TILE + threadIdx.x * 4;
    int v[4];
    int s = 0;
    #pragma unroll
    for (int j = 0; j < 4; j++) {
        int i = base + j;
        v[j] = (i < n) ? deg[i] : 0;
        s += v[j];
    }
    sdata[threadIdx.x] = s;
    __syncthreads();
    for (int off = 1; off < 256; off <<= 1) {
        int t = (threadIdx.x >= off) ? sdata[threadIdx.x - off] : 0;
        __syncthreads();
        sdata[threadIdx.x] += t;
        __syncthreads();
    }
    int excl = sdata[threadIdx.x] - s + bsums[blockIdx.x];
    #pragma unroll
    for (int j = 0; j < 4; j++) {
        int i = base + j;
        if (i <= n) offsets[i] = excl;
        if (i < n) cursor[i] = excl;
        excl += v[j];
    }
}

__global__ void fill_kernel(const int* __restrict__ esrc, const int* __restrict__ edst,
                            int* __restrict__ cursor, int* __restrict__ csr_src, int n_edges) {
    int e = blockIdx.x * 256 + threadIdx.x;
    if (e >= n_edges) return;
    int pos = atomicAdd(&cursor[edst[e]], 1);
    csr_src[pos] = esrc[e];
}

// ---------------- AGG: gather + sum -> z (bf16, plain row-major) ----------------
// 256-thread blocks, no LDS, no barriers. One row per 8 lanes; 16B fp8 per lane.
__global__ __launch_bounds__(256) void agg_kernel(
        const int* __restrict__ offsets, const int* __restrict__ csr_src,
        const unsigned char* __restrict__ h_in, short* __restrict__ z, int n_rows) {
    const int t   = blockIdx.x * 256 + threadIdx.x;
    const int row = t >> 3;
    const int l8  = t & 7;
    if (row >= n_rows) return;

    float acc[16];
    {   // self
        uint4 w = *reinterpret_cast<const uint4*>(h_in + (size_t)row * D + l8 * 16);
        unsigned int wd[4] = {w.x, w.y, w.z, w.w};
        #pragma unroll
        for (int k = 0; k < 4; k++) {
            floatx2 lo = __builtin_amdgcn_cvt_pk_f32_fp8((int)wd[k], false);
            floatx2 hi = __builtin_amdgcn_cvt_pk_f32_fp8((int)wd[k], true);
            acc[4 * k]     = lo[0]; acc[4 * k + 1] = lo[1];
            acc[4 * k + 2] = hi[0]; acc[4 * k + 3] = hi[1];
        }
    }
    int e   = offsets[row];
    int end = offsets[row + 1];
    for (; e + 3 < end; e += 4) {
        int sA = csr_src[e];
        int sB = csr_src[e + 1];
        int sC = csr_src[e + 2];
        int sD = csr_src[e + 3];
        uint4 wA = *reinterpret_cast<const uint4*>(h_in + (size_t)sA * D + l8 * 16);
        uint4 wB = *reinterpret_cast<const uint4*>(h_in + (size_t)sB * D + l8 * 16);
        uint4 wC = *reinterpret_cast<const uint4*>(h_in + (size_t)sC * D + l8 * 16);
        uint4 wD = *reinterpret_cast<const uint4*>(h_in + (size_t)sD * D + l8 * 16);
        unsigned int da[4] = {wA.x, wA.y, wA.z, wA.w};
        unsigned int db[4] = {wB.x, wB.y, wB.z, wB.w};
        unsigned int dc[4] = {wC.x, wC.y, wC.z, wC.w};
        unsigned int dd[4] = {wD.x, wD.y, wD.z, wD.w};
        #pragma unroll
        for (int k = 0; k < 4; k++) {
            floatx2 alo = __builtin_amdgcn_cvt_pk_f32_fp8((int)da[k], false);
            floatx2 ahi = __builtin_amdgcn_cvt_pk_f32_fp8((int)da[k], true);
            floatx2 blo = __builtin_amdgcn_cvt_pk_f32_fp8((int)db[k], false);
            floatx2 bhi = __builtin_amdgcn_cvt_pk_f32_fp8((int)db[k], true);
            floatx2 clo = __builtin_amdgcn_cvt_pk_f32_fp8((int)dc[k], false);
            floatx2 chi = __builtin_amdgcn_cvt_pk_f32_fp8((int)dc[k], true);
            floatx2 dlo = __builtin_amdgcn_cvt_pk_f32_fp8((int)dd[k], false);
            floatx2 dhi = __builtin_amdgcn_cvt_pk_f32_fp8((int)dd[k], true);
            acc[4 * k]     += (alo[0] + blo[0]) + (clo[0] + dlo[0]);
            acc[4 * k + 1] += (alo[1] + blo[1]) + (clo[1] + dlo[1]);
            acc[4 * k + 2] += (ahi[0] + bhi[0]) + (chi[0] + dhi[0]);
            acc[4 * k + 3] += (ahi[1] + bhi[1]) + (chi[1] + dhi[1]);
        }
    }
    for (; e < end; e++) {
        int sA = csr_src[e];
        uint4 wA = *reinterpret_cast<const uint4*>(h_in + (size_t)sA * D + l8 * 16);
        unsigned int da[4] = {wA.x, wA.y, wA.z, wA.w};
        #pragma unroll
        for (int k = 0; k < 4; k++) {
            floatx2 alo = __builtin_amdgcn_cvt_pk_f32_fp8((int)da[k], false);
            floatx2 ahi = __builtin_amdgcn_cvt_pk_f32_fp8((int)da[k], true);
            acc[4 * k]     += alo[0];
            acc[4 * k + 1] += alo[1];
            acc[4 * k + 2] += ahi[0];
            acc[4 * k + 3] += ahi[1];
        }
    }
    // undo the x16 storage scale (power-of-2: exact), round to bf16, store plain row-major
    short8 o0, o1;
    #pragma unroll
    for (int j = 0; j < 8; j++) {
        o0[j] = (short)bf16_rne(acc[j] * HSCALE_INV);
        o1[j] = (short)bf16_rne(acc[8 + j] * HSCALE_INV);
    }
    *reinterpret_cast<short8*>(z + (size_t)row * D + l8 * 16)     = o0;
    *reinterpret_cast<short8*>(z + (size_t)row * D + l8 * 16 + 8) = o1;
}

// ---------------- GEMM1: z -> relu(z@Wa+ba) = t, IN-PLACE over z. No LDS, no barriers. ----------------
// R8 lesson: MLP is memory-LATENCY-serialized (ds_read->MFMA round trips); fix = no LDS at all.
// Per wave: B-fragments for one 64-col half live in 64 VGPRs (loaded from L2-hot wt, once per
// tile+half; asm-opaqued pointer blocks LICM from hoisting both halves = 128 regs + spill).
// A-frags (full 128-col row) loaded BEFORE any store -> in-place t over z is safe; tiles
// partition rows across waves. 4 waves/SIMD (VGPR<=128), 4096 waves, ~1.5 tiles each.
__global__ __launch_bounds__(256, 4) void gemm1_kernel(
        short* __restrict__ zt, const short* __restrict__ wta,
        const float* __restrict__ ba, int n_rows, int n_tiles) {
    const int tid  = threadIdx.x;
    const int lane = tid & 63;
    const int wv   = tid >> 6;
    const int lm   = lane & 15;
    const int quad = lane >> 4;

    float bva[8];
    #pragma unroll
    for (int j = 0; j < 8; j++) bva[j] = ba[j * 16 + lm];

    const int wave_id = blockIdx.x * 4 + wv;
    const int n_waves = gridDim.x * 4;
    for (int tile = wave_id; tile < n_tiles; tile += n_waves) {
        const int row0 = tile * 16;
        const int r    = row0 + lm;
        short8 av[4];                        // the wave's 16 full rows of z
        #pragma unroll
        for (int ks = 0; ks < 4; ks++) {
            if (r < n_rows)
                av[ks] = *reinterpret_cast<const short8*>(zt + (size_t)r * D + (ks * 4 + quad) * 8);
            else
                av[ks] = short8{0, 0, 0, 0, 0, 0, 0, 0};
        }
        const short* wp = wta;
        asm volatile("" : "+s"(wp));        // opaque: keep B-frag loads inside the loop
        #pragma unroll
        for (int h = 0; h < 2; h++) {
            short8 bw[4][4];
            #pragma unroll
            for (int ks = 0; ks < 4; ks++)
                #pragma unroll
                for (int cs = 0; cs < 4; cs++) {
                    int nn = h * 64 + cs * 16 + lm;
                    bw[ks][cs] = *reinterpret_cast<const short8*>(
                        wp + (size_t)nn * D + (ks * 4 + quad) * 8);
                }
            floatx4 acc[4];
            #pragma unroll
            for (int cs = 0; cs < 4; cs++) acc[cs] = floatx4{0.f, 0.f, 0.f, 0.f};
            #pragma unroll
            for (int ks = 0; ks < 4; ks++)
                #pragma unroll
                for (int cs = 0; cs < 4; cs++)
                    acc[cs] = __builtin_amdgcn_mfma_f32_16x16x32_bf16(av[ks], bw[ks][cs], acc[cs], 0, 0, 0);
            #pragma unroll
            for (int cs = 0; cs < 4; cs++) {
                int col = h * 64 + cs * 16 + lm;
                float bv = bva[h * 4 + cs];
                #pragma unroll
                for (int reg = 0; reg < 4; reg++) {
                    int rr = row0 + quad * 4 + reg;
                    if (rr < n_rows)
                        zt[(size_t)rr * D + col] = (short)bf16_rne(fmaxf(acc[cs][reg] + bv, 0.f));
                }
            }
        }
    }
}

// ---------------- GEMM2: t -> relu(t@Wb+bb) -> h_out (fp8) [+ register pool on last layer] ----------------
__global__ __launch_bounds__(256, 4) void gemm2_kernel(
        const short* __restrict__ t, const short* __restrict__ wtb,
        const float* __restrict__ bb, unsigned char* __restrict__ h_out,
        float* __restrict__ pooled_accum, int n_rows, int n_tiles) {
    const int tid  = threadIdx.x;
    const int lane = tid & 63;
    const int wv   = tid >> 6;
    const int lm   = lane & 15;
    const int quad = lane >> 4;

    float bvb[8];
    #pragma unroll
    for (int j = 0; j < 8; j++) bvb[j] = bb[j * 16 + lm];

    float poolsum[8];
    #pragma unroll
    for (int j = 0; j < 8; j++) poolsum[j] = 0.f;

    const int wave_id = blockIdx.x * 4 + wv;
    const int n_waves = gridDim.x * 4;
    for (int tile = wave_id; tile < n_tiles; tile += n_waves) {
        const int row0 = tile * 16;
        const int r    = row0 + lm;
        short8 av[4];
        #pragma unroll
        for (int ks = 0; ks < 4; ks++) {
            if (r < n_rows)
                av[ks] = *reinterpret_cast<const short8*>(t + (size_t)r * D + (ks * 4 + quad) * 8);
            else
                av[ks] = short8{0, 0, 0, 0, 0, 0, 0, 0};
        }
        const short* wp = wtb;
        asm volatile("" : "+s"(wp));        // opaque: keep B-frag loads inside the loop
        #pragma unroll
        for (int h = 0; h < 2; h++) {
            short8 bw[4][4];
            #pragma unroll
            for (int ks = 0; ks < 4; ks++)
                #pragma unroll
                for (int cs = 0; cs < 4; cs++) {
                    int nn = h * 64 + cs * 16 + lm;
                    bw[ks][cs] = *reinterpret_cast<const short8*>(
                        wp + (size_t)nn * D + (ks * 4 + quad) * 8);
                }
            floatx4 acc[4];
            #pragma unroll
            for (int cs = 0; cs < 4; cs++) acc[cs] = floatx4{0.f, 0.f, 0.f, 0.f};
            #pragma unroll
            for (int ks = 0; ks < 4; ks++)
                #pragma unroll
                for (int cs = 0; cs < 4; cs++)
                    acc[cs] = __builtin_amdgcn_mfma_f32_16x16x32_bf16(av[ks], bw[ks][cs], acc[cs], 0, 0, 0);
            #pragma unroll
            for (int cs = 0; cs < 4; cs++) {
                int col = h * 64 + cs * 16 + lm;
                float bv = bvb[h * 4 + cs];
                #pragma unroll
                for (int reg = 0; reg < 4; reg++) {
                    int rr = row0 + quad * 4 + reg;
                    if (rr < n_rows) {
                        float v = fmaxf(acc[cs][reg] + bv, 0.f);
                        if (h_out != nullptr) {
                            float sv = v * HSCALE;
                            int pw = __builtin_amdgcn_cvt_pk_fp8_f32(sv, sv, 0, false);
                            h_out[(size_t)rr * D + col] = (unsigned char)(pw & 0xff);
                        }
                        poolsum[h * 4 + cs] += v;
                    }
                }
            }
        }
    }

    if (pooled_accum != nullptr) {
        #pragma unroll
        for (int j = 0; j < 8; j++) {
            float v = poolsum[j];
            v += __shfl_xor(v, 16);
            v += __shfl_xor(v, 32);
            if (quad == 0) atomicAdd(&pooled_accum[j * 16 + lm], v);
        }
    }
}

// ---------------- final linear (fp32 exact) ----------------
__global__ void final_kernel(const float* __restrict__ pooled, const float* __restrict__ Wlin,
                             const float* __restrict__ blin, float* __restrict__ out) {
    const int j = threadIdx.x;
    __shared__ float p[D];
    p[j] = pooled[j];
    __syncthreads();
    float s = blin[j];
    #pragma unroll 8
    for (int k = 0; k < D; k++) s += p[k] * Wlin[k * D + j];
    out[j] = s;
}

extern "C" void kernel_launch(void* const* d_in, const int* in_sizes, int n_in,
                              void* d_out, int out_size, void* d_ws, size_t ws_size,
                              hipStream_t stream) {
    const int*   x    = (const int*)d_in[0];
    const int*   ei   = (const int*)d_in[1];
    const float* emb  = (const float*)d_in[2];
    const float* Wa   = (const float*)d_in[3];
    const float* ba   = (const float*)d_in[4];
    const float* Wb   = (const float*)d_in[5];
    const float* bb   = (const float*)d_in[6];
    const float* Wlin = (const float*)d_in[7];
    const float* blin = (const float*)d_in[8];
    float* out = (float*)d_out;

    const int N = in_sizes[0];
    const int E = in_sizes[1] / 2;
    const int* esrc = ei;
    const int* edst = ei + E;

    // workspace: H0 | H1 (fp8) | z/t (bf16, in-place) | pooled | deg | offsets | cursor | bsums | csr_src | wt
    unsigned char* H0 = (unsigned char*)d_ws;           // N*128 bytes
    unsigned char* H1 = H0 + (size_t)N * D;             // N*128 bytes
    short* zbuf = (short*)(H1 + (size_t)N * D);         // N*128 shorts (25.6 MB), z then t
    float* pooled = (float*)(zbuf + (size_t)N * D);     // 128
    int* deg     = (int*)(pooled + 128);                // N
    int* offsets = deg + N;                             // N+1
    int* cursor  = offsets + (N + 1);                   // N
    int* bsums   = cursor + N;                          // 4096
    int* csr_src = bsums + 4096;                        // E
    uintptr_t wt_addr = ((uintptr_t)(csr_src + E) + 15) & ~(uintptr_t)15;
    short* wt = (short*)wt_addr;                        // [10][128][128] bf16

    const int scan_blocks = (N + 1 + SCAN_TILE - 1) / SCAN_TILE;

    // zero pooled[128] + deg[N] in one contiguous memset (graph-capture-safe)
    hipMemsetAsync(pooled, 0, (size_t)(128 + N) * sizeof(int), stream);

    prepA_kernel<<<1024, 256, 0, stream>>>(x, emb, Wa, Wb, edst, H0, wt, deg, N, E);
    scan_sums_kernel<<<scan_blocks, 256, 0, stream>>>(deg, bsums, N);
    scan_bsums_kernel<<<1, 256, 0, stream>>>(bsums, scan_blocks);
    scan_final_kernel<<<scan_blocks, 256, 0, stream>>>(deg, bsums, offsets, cursor, N);
    fill_kernel<<<(E + 255) / 256, 256, 0, stream>>>(esrc, edst, cursor, csr_src, E);

    const int agg_blocks  = (N * 8 + 255) / 256;
    const int n_tiles     = (N + 15) / 16;
    const int gemm_blocks = 1024;                       // 4096 waves (all resident at 4 w/SIMD)
    unsigned char* hin = H0; unsigned char* hout = H1;
    for (int l = 0; l < NLAYERS; l++) {
        const bool last = (l == NLAYERS - 1);
        float* pacc = last ? pooled : nullptr;
        unsigned char* hdst = last ? nullptr : hout;   // last layer: output only feeds the pool
        agg_kernel<<<agg_blocks, 256, 0, stream>>>(offsets, csr_src, hin, zbuf, N);
        gemm1_kernel<<<gemm_blocks, 256, 0, stream>>>(
            zbuf, wt + (size_t)(2 * l) * D * D, ba + (size_t)l * D, N, n_tiles);
        gemm2_kernel<<<gemm_blocks, 256, 0, stream>>>(
            zbuf, wt + (size_t)(2 * l + 1) * D * D, bb + (size_t)l * D, hdst, pacc, N, n_tiles);
        unsigned char* tmp = hin; hin = hout; hout = tmp;
    }

    final_kernel<<<1, 128, 0, stream>>>(pooled, Wlin, blin, out);
}

// Round 10
// 390.157 us; speedup vs baseline: 1.8160x; 1.8160x over previous
//
#include <hip/hip_runtime.h>

#define D 128
#define NLAYERS 5

using short8  = __attribute__((ext_vector_type(8))) short;
using short4v = __attribute__((ext_vector_type(4))) short;
using floatx4 = __attribute__((ext_vector_type(4))) float;
using floatx2 = __attribute__((ext_vector_type(2))) float;

__device__ __forceinline__ unsigned bf16_rne(float x) {
    unsigned u = __float_as_uint(x);
    return (u + 0x7fffu + ((u >> 16) & 1u)) >> 16;
}
__device__ __forceinline__ float bf16_to_f32(short s) {
    return __uint_as_float(((unsigned)(unsigned short)s) << 16);
}

// H is stored as fp8 e4m3 with a fixed x16 scale (power of 2 => scaling is exact).
#define HSCALE 16.0f
#define HSCALE_INV 0.0625f

// ---------------- prepA: W transpose/bf16 + H0 gather (fp8) + fused edge histogram ----------------
__global__ void prepA_kernel(const int* __restrict__ x, const float* __restrict__ emb,
                             const float* __restrict__ Wa, const float* __restrict__ Wb,
                             const int* __restrict__ edst,
                             unsigned char* __restrict__ H0, short* __restrict__ wt,
                             int* __restrict__ deg,
                             int n_nodes, int n_edges) {
    const int gtid = blockIdx.x * 256 + threadIdx.x;
    const int gsz  = gridDim.x * 256;
    for (int g = gtid; g < 2 * NLAYERS * D * D; g += gsz) {
        int mat = g >> 14, idx = g & 16383;
        int n = idx >> 7, k = idx & 127;
        const float* W = (mat & 1) ? (Wb + (size_t)(mat >> 1) * D * D)
                                   : (Wa + (size_t)(mat >> 1) * D * D);
        wt[g] = (short)bf16_rne(W[k * D + n]);
    }
    for (int t = gtid; t < n_nodes * 32; t += gsz) {
        int node = t >> 5, lane = t & 31;
        int s = x[node];
        const float4 v = *reinterpret_cast<const float4*>(emb + (size_t)s * D + lane * 4);
        int w = __builtin_amdgcn_cvt_pk_fp8_f32(v.x * HSCALE, v.y * HSCALE, 0, false);
        w = __builtin_amdgcn_cvt_pk_fp8_f32(v.z * HSCALE, v.w * HSCALE, w, true);
        reinterpret_cast<unsigned int*>(H0)[(size_t)node * 32 + lane] = (unsigned int)w;
    }
    for (int e = gtid; e < n_edges; e += gsz) atomicAdd(&deg[edst[e]], 1);
}

#define SCAN_TILE 1024
__global__ void scan_sums_kernel(const int* __restrict__ deg, int* __restrict__ bsums, int n) {
    __shared__ int red[256];
    int base = blockIdx.x * SCAN_TILE + threadIdx.x * 4;
    int s = 0;
    #pragma unroll
    for (int j = 0; j < 4; j++) {
        int i = base + j;
        if (i < n) s += deg[i];
    }
    red[threadIdx.x] = s;
    __syncthreads();
    for (int off = 128; off > 0; off >>= 1) {
        if (threadIdx.x < off) red[threadIdx.x] += red[threadIdx.x + off];
        __syncthreads();
    }
    if (threadIdx.x == 0) bsums[blockIdx.x] = red[0];
}

__global__ void scan_bsums_kernel(int* __restrict__ bsums, int nblocks) {
    __shared__ int sdata[256];
    int carry = 0;
    for (int base = 0; base < nblocks; base += 256) {
        int i = base + threadIdx.x;
        int v = (i < nblocks) ? bsums[i] : 0;
        sdata[threadIdx.x] = v;
        __syncthreads();
        for (int off = 1; off < 256; off <<= 1) {
            int t = (threadIdx.x >= off) ? sdata[threadIdx.x - off] : 0;
            __syncthreads();
            sdata[threadIdx.x] += t;
            __syncthreads();
        }
        int incl = sdata[threadIdx.x];
        if (i < nblocks) bsums[i] = carry + incl - v;
        carry += sdata[255];
        __syncthreads();
    }
}

__global__ void scan_final_kernel(const int* __restrict__ deg, const int* __restrict__ bsums,
                                  int* __restrict__ offsets, int* __restrict__ cursor, int n) {
    __shared__ int sdata[256];
    int base = blockIdx.x * SCAN_TILE + threadIdx.x * 4;
    int v[4];
    int s = 0;
    #pragma unroll
    for (int j = 0; j < 4; j++) {
        int i = base + j;
        v[j] = (i < n) ? deg[i] : 0;
        s += v[j];
    }
    sdata[threadIdx.x] = s;
    __syncthreads();
    for (int off = 1; off < 256; off <<= 1) {
        int t = (threadIdx.x >= off) ? sdata[threadIdx.x - off] : 0;
        __syncthreads();
        sdata[threadIdx.x] += t;
        __syncthreads();
    }
    int excl = sdata[threadIdx.x] - s + bsums[blockIdx.x];
    #pragma unroll
    for (int j = 0; j < 4; j++) {
        int i = base + j;
        if (i <= n) offsets[i] = excl;
        if (i < n) cursor[i] = excl;
        excl += v[j];
    }
}

__global__ void fill_kernel(const int* __restrict__ esrc, const int* __restrict__ edst,
                            int* __restrict__ cursor, int* __restrict__ csr_src, int n_edges) {
    int e = blockIdx.x * 256 + threadIdx.x;
    if (e >= n_edges) return;
    int pos = atomicAdd(&cursor[edst[e]], 1);
    csr_src[pos] = esrc[e];
}

// aggregate one row (fp8 h_in) into acc[16]; R5's exact edge order and add tree
__device__ __forceinline__ void agg_row(const int* __restrict__ offsets,
                                        const int* __restrict__ csr_src,
                                        const unsigned char* __restrict__ h_in,
                                        int gr, int l8, float* acc) {
    {   // self
        uint4 w = *reinterpret_cast<const uint4*>(h_in + (size_t)gr * D + l8 * 16);
        unsigned int wd[4] = {w.x, w.y, w.z, w.w};
        #pragma unroll
        for (int k = 0; k < 4; k++) {
            floatx2 lo = __builtin_amdgcn_cvt_pk_f32_fp8((int)wd[k], false);
            floatx2 hi = __builtin_amdgcn_cvt_pk_f32_fp8((int)wd[k], true);
            acc[4 * k]     = lo[0]; acc[4 * k + 1] = lo[1];
            acc[4 * k + 2] = hi[0]; acc[4 * k + 3] = hi[1];
        }
    }
    int e   = offsets[gr];
    int end = offsets[gr + 1];
    for (; e + 3 < end; e += 4) {
        int sA = csr_src[e];
        int sB = csr_src[e + 1];
        int sC = csr_src[e + 2];
        int sD = csr_src[e + 3];
        uint4 wA = *reinterpret_cast<const uint4*>(h_in + (size_t)sA * D + l8 * 16);
        uint4 wB = *reinterpret_cast<const uint4*>(h_in + (size_t)sB * D + l8 * 16);
        uint4 wC = *reinterpret_cast<const uint4*>(h_in + (size_t)sC * D + l8 * 16);
        uint4 wD = *reinterpret_cast<const uint4*>(h_in + (size_t)sD * D + l8 * 16);
        unsigned int da[4] = {wA.x, wA.y, wA.z, wA.w};
        unsigned int db[4] = {wB.x, wB.y, wB.z, wB.w};
        unsigned int dc[4] = {wC.x, wC.y, wC.z, wC.w};
        unsigned int dd[4] = {wD.x, wD.y, wD.z, wD.w};
        #pragma unroll
        for (int k = 0; k < 4; k++) {
            floatx2 alo = __builtin_amdgcn_cvt_pk_f32_fp8((int)da[k], false);
            floatx2 ahi = __builtin_amdgcn_cvt_pk_f32_fp8((int)da[k], true);
            floatx2 blo = __builtin_amdgcn_cvt_pk_f32_fp8((int)db[k], false);
            floatx2 bhi = __builtin_amdgcn_cvt_pk_f32_fp8((int)db[k], true);
            floatx2 clo = __builtin_amdgcn_cvt_pk_f32_fp8((int)dc[k], false);
            floatx2 chi = __builtin_amdgcn_cvt_pk_f32_fp8((int)dc[k], true);
            floatx2 dlo = __builtin_amdgcn_cvt_pk_f32_fp8((int)dd[k], false);
            floatx2 dhi = __builtin_amdgcn_cvt_pk_f32_fp8((int)dd[k], true);
            acc[4 * k]     += (alo[0] + blo[0]) + (clo[0] + dlo[0]);
            acc[4 * k + 1] += (alo[1] + blo[1]) + (clo[1] + dlo[1]);
            acc[4 * k + 2] += (ahi[0] + bhi[0]) + (chi[0] + dhi[0]);
            acc[4 * k + 3] += (ahi[1] + bhi[1]) + (chi[1] + dhi[1]);
        }
    }
    for (; e < end; e++) {
        int sA = csr_src[e];
        uint4 wA = *reinterpret_cast<const uint4*>(h_in + (size_t)sA * D + l8 * 16);
        unsigned int da[4] = {wA.x, wA.y, wA.z, wA.w};
        #pragma unroll
        for (int k = 0; k < 4; k++) {
            floatx2 alo = __builtin_amdgcn_cvt_pk_f32_fp8((int)da[k], false);
            floatx2 ahi = __builtin_amdgcn_cvt_pk_f32_fp8((int)da[k], true);
            acc[4 * k]     += alo[0];
            acc[4 * k + 1] += alo[1];
            acc[4 * k + 2] += ahi[0];
            acc[4 * k + 3] += ahi[1];
        }
    }
}

// ---------------- fused layer, 128 rows/block (R5 structure, amortized 2x) ----------------
// R9 lessons: no-LDS/global-weight variants are latency-dead; R5 fused (64 rows) = best known.
// This round amortizes R5's per-block overheads over 2x rows: weight staging 100->50 MB/layer,
// half the barrier drains, and each B-fragment ds_read now feeds TWO row-blocks (rb=0,1).
// Agg: each thread does rows g and g+64 sequentially with the exact R5 per-row loop.
// LDS: zsh 32KB (128 rows) + one weight buffer 32KB = 64KB -> 2 blocks/CU (4 waves/SIMD).
// wb overwrites wa between GEMM1 and GEMM2 (hides under bias/relu). Last layer: h_out null.
// zsh 16B chunks XOR-swizzled: chunk c of row r at (c ^ (r&15)).
__global__ __launch_bounds__(512, 4) void layer_kernel(
        const int* __restrict__ offsets, const int* __restrict__ csr_src,
        const unsigned char* __restrict__ h_in, const short* __restrict__ wta,
        const short* __restrict__ wtb, const float* __restrict__ ba,
        const float* __restrict__ bb, unsigned char* __restrict__ h_out,
        float* __restrict__ pooled_accum, int n_rows) {
    __shared__ __align__(16) short zsh[128 * 128];    // 32 KB: z tile, then t tile, then pool scratch
    __shared__ __align__(16) short wsh[128 * 128];    // 32 KB: wa for GEMM1, then wb for GEMM2

    const int tid  = threadIdx.x;
    const int row0 = blockIdx.x * 128;

    #pragma unroll
    for (int i = 0; i < 4; i++) {
        int g = i * 512 + tid;
        int n = g >> 4, c = g & 15;
        int off = (n * 16 + (c ^ (n & 15))) * 8;
        *reinterpret_cast<short8*>(&wsh[off]) =
            *reinterpret_cast<const short8*>(wta + n * D + c * 8);
    }

    {
        const int g  = tid >> 3;         // 0..63
        const int l8 = tid & 7;
        #pragma unroll
        for (int half = 0; half < 2; half++) {
            const int r  = g + half * 64;       // local row 0..127
            const int gr = row0 + r;
            float acc[16];
            if (gr < n_rows) {
                agg_row(offsets, csr_src, h_in, gr, l8, acc);
            } else {
                #pragma unroll
                for (int j = 0; j < 16; j++) acc[j] = 0.f;
            }
            short8 o0, o1;
            #pragma unroll
            for (int j = 0; j < 8; j++) {
                o0[j] = (short)bf16_rne(acc[j] * HSCALE_INV);
                o1[j] = (short)bf16_rne(acc[8 + j] * HSCALE_INV);
            }
            const int c0i = 2 * l8, c1i = 2 * l8 + 1;
            *reinterpret_cast<short8*>(&zsh[(r * 16 + (c0i ^ (r & 15))) * 8]) = o0;
            *reinterpret_cast<short8*>(&zsh[(r * 16 + (c1i ^ (r & 15))) * 8]) = o1;
        }
    }
    __syncthreads();

    const int lane = tid & 63;
    const int wave = tid >> 6;
    const int wr   = wave >> 1;          // 0..3: 32-row stripe
    const int wc   = wave & 1;           // 0..1: 64-col half
    const int lm   = lane & 15;
    const int quad = lane >> 4;

    floatx4 acc1[2][4];
    #pragma unroll
    for (int rb = 0; rb < 2; rb++)
        #pragma unroll
        for (int cs = 0; cs < 4; cs++) acc1[rb][cs] = floatx4{0.f, 0.f, 0.f, 0.f};
    {
        short8 av[2][4];
        #pragma unroll
        for (int rb = 0; rb < 2; rb++) {
            const int r = wr * 32 + rb * 16 + lm;
            #pragma unroll
            for (int ks = 0; ks < 4; ks++) {
                const int c = ks * 4 + quad;
                av[rb][ks] = *reinterpret_cast<const short8*>(&zsh[(r * 16 + (c ^ (r & 15))) * 8]);
            }
        }
        #pragma unroll
        for (int ks = 0; ks < 4; ks++) {
            const int c = ks * 4 + quad;
            #pragma unroll
            for (int cs = 0; cs < 4; cs++) {
                int nn = wc * 64 + cs * 16 + lm;
                short8 bv = *reinterpret_cast<const short8*>(&wsh[(nn * 16 + (c ^ (nn & 15))) * 8]);
                acc1[0][cs] = __builtin_amdgcn_mfma_f32_16x16x32_bf16(av[0][ks], bv, acc1[0][cs], 0, 0, 0);
                acc1[1][cs] = __builtin_amdgcn_mfma_f32_16x16x32_bf16(av[1][ks], bv, acc1[1][cs], 0, 0, 0);
            }
        }
    }
    __syncthreads();   // all wa + z1 reads done; wsh and zsh may be overwritten

    // load wb over wa (L2-hot; hides under the bias/relu VALU work below)
    #pragma unroll
    for (int i = 0; i < 4; i++) {
        int g = i * 512 + tid;
        int n = g >> 4, c = g & 15;
        int off = (n * 16 + (c ^ (n & 15))) * 8;
        *reinterpret_cast<short8*>(&wsh[off]) =
            *reinterpret_cast<const short8*>(wtb + n * D + c * 8);
    }

    #pragma unroll
    for (int cs = 0; cs < 4; cs++) {
        int col = wc * 64 + cs * 16 + lm;
        float bva = ba[col];
        int cj = col >> 3, ci = col & 7;
        #pragma unroll
        for (int rb = 0; rb < 2; rb++)
            #pragma unroll
            for (int reg = 0; reg < 4; reg++) {
                int r = wr * 32 + rb * 16 + quad * 4 + reg;
                float v = fmaxf(acc1[rb][cs][reg] + bva, 0.f);
                zsh[(r * 16 + (cj ^ (r & 15))) * 8 + ci] = (short)bf16_rne(v);
            }
    }
    __syncthreads();

    floatx4 acc2[2][4];
    #pragma unroll
    for (int rb = 0; rb < 2; rb++)
        #pragma unroll
        for (int cs = 0; cs < 4; cs++) acc2[rb][cs] = floatx4{0.f, 0.f, 0.f, 0.f};
    {
        short8 av[2][4];
        #pragma unroll
        for (int rb = 0; rb < 2; rb++) {
            const int r = wr * 32 + rb * 16 + lm;
            #pragma unroll
            for (int ks = 0; ks < 4; ks++) {
                const int c = ks * 4 + quad;
                av[rb][ks] = *reinterpret_cast<const short8*>(&zsh[(r * 16 + (c ^ (r & 15))) * 8]);
            }
        }
        #pragma unroll
        for (int ks = 0; ks < 4; ks++) {
            const int c = ks * 4 + quad;
            #pragma unroll
            for (int cs = 0; cs < 4; cs++) {
                int nn = wc * 64 + cs * 16 + lm;
                short8 bv = *reinterpret_cast<const short8*>(&wsh[(nn * 16 + (c ^ (nn & 15))) * 8]);
                acc2[0][cs] = __builtin_amdgcn_mfma_f32_16x16x32_bf16(av[0][ks], bv, acc2[0][cs], 0, 0, 0);
                acc2[1][cs] = __builtin_amdgcn_mfma_f32_16x16x32_bf16(av[1][ks], bv, acc2[1][cs], 0, 0, 0);
            }
        }
    }

    float psum[4];   // per-thread, per-cs column partial (only used on last layer)
    #pragma unroll
    for (int cs = 0; cs < 4; cs++) {
        int col = wc * 64 + cs * 16 + lm;
        float bvb = bb[col];
        float s = 0.f;
        #pragma unroll
        for (int rb = 0; rb < 2; rb++)
            #pragma unroll
            for (int reg = 0; reg < 4; reg++) {
                int r = row0 + wr * 32 + rb * 16 + quad * 4 + reg;
                if (r < n_rows) {
                    float v = fmaxf(acc2[rb][cs][reg] + bvb, 0.f);
                    if (h_out != nullptr) {
                        float sv = v * HSCALE;
                        int pw = __builtin_amdgcn_cvt_pk_fp8_f32(sv, sv, 0, false);
                        h_out[(size_t)r * D + col] = (unsigned char)(pw & 0xff);
                    }
                    s += v;   // pool the f32 value (last layer stores nothing)
                }
            }
        psum[cs] = s;
    }

    if (pooled_accum != nullptr) {
        __syncthreads();                 // all gemm2 zsh reads done; reuse zsh as f32 scratch
        float* part = (float*)zsh;       // [16][128] floats = 8KB
        #pragma unroll
        for (int cs = 0; cs < 4; cs++)
            part[(wr * 4 + quad) * 128 + wc * 64 + cs * 16 + lm] = psum[cs];
        __syncthreads();
        if (tid < 128) {
            float s = 0.f;
            #pragma unroll
            for (int g = 0; g < 16; g++) s += part[g * 128 + tid];
            atomicAdd(&pooled_accum[tid], s);
        }
    }
}

// ---------------- final linear (fp32 exact) ----------------
__global__ void final_kernel(const float* __restrict__ pooled, const float* __restrict__ Wlin,
                             const float* __restrict__ blin, float* __restrict__ out) {
    const int j = threadIdx.x;
    __shared__ float p[D];
    p[j] = pooled[j];
    __syncthreads();
    float s = blin[j];
    #pragma unroll 8
    for (int k = 0; k < D; k++) s += p[k] * Wlin[k * D + j];
    out[j] = s;
}

extern "C" void kernel_launch(void* const* d_in, const int* in_sizes, int n_in,
                              void* d_out, int out_size, void* d_ws, size_t ws_size,
                              hipStream_t stream) {
    const int*   x    = (const int*)d_in[0];
    const int*   ei   = (const int*)d_in[1];
    const float* emb  = (const float*)d_in[2];
    const float* Wa   = (const float*)d_in[3];
    const float* ba   = (const float*)d_in[4];
    const float* Wb   = (const float*)d_in[5];
    const float* bb   = (const float*)d_in[6];
    const float* Wlin = (const float*)d_in[7];
    const float* blin = (const float*)d_in[8];
    float* out = (float*)d_out;

    const int N = in_sizes[0];
    const int E = in_sizes[1] / 2;
    const int* esrc = ei;
    const int* edst = ei + E;

    // workspace: H0 | H1 (fp8, N*128 bytes each) | pooled | deg | offsets | cursor | bsums | csr_src | wt
    unsigned char* H0 = (unsigned char*)d_ws;           // N*128 bytes
    unsigned char* H1 = H0 + (size_t)N * D;             // N*128 bytes
    float* pooled = (float*)(H1 + (size_t)N * D);       // 128
    int* deg     = (int*)(pooled + 128);                // N
    int* offsets = deg + N;                             // N+1
    int* cursor  = offsets + (N + 1);                   // N
    int* bsums   = cursor + N;                          // 4096
    int* csr_src = bsums + 4096;                        // E
    uintptr_t wt_addr = ((uintptr_t)(csr_src + E) + 15) & ~(uintptr_t)15;
    short* wt = (short*)wt_addr;                        // [10][128][128] bf16

    const int scan_blocks = (N + 1 + SCAN_TILE - 1) / SCAN_TILE;

    // zero pooled[128] + deg[N] in one contiguous memset (graph-capture-safe)
    hipMemsetAsync(pooled, 0, (size_t)(128 + N) * sizeof(int), stream);

    prepA_kernel<<<1024, 256, 0, stream>>>(x, emb, Wa, Wb, edst, H0, wt, deg, N, E);
    scan_sums_kernel<<<scan_blocks, 256, 0, stream>>>(deg, bsums, N);
    scan_bsums_kernel<<<1, 256, 0, stream>>>(bsums, scan_blocks);
    scan_final_kernel<<<scan_blocks, 256, 0, stream>>>(deg, bsums, offsets, cursor, N);
    fill_kernel<<<(E + 255) / 256, 256, 0, stream>>>(esrc, edst, cursor, csr_src, E);

    const int layer_blocks = (N + 127) / 128;
    unsigned char* hin = H0; unsigned char* hout = H1;
    for (int l = 0; l < NLAYERS; l++) {
        const bool last = (l == NLAYERS - 1);
        float* pacc = last ? pooled : nullptr;
        unsigned char* hdst = last ? nullptr : hout;   // last layer: output only feeds the pool
        layer_kernel<<<layer_blocks, 512, 0, stream>>>(
            offsets, csr_src, hin,
            wt + (size_t)(2 * l) * D * D, wt + (size_t)(2 * l + 1) * D * D,
            ba + (size_t)l * D, bb + (size_t)l * D, hdst, pacc, N);
        unsigned char* tmp = hin; hin = hout; hout = tmp;
    }

    final_kernel<<<1, 128, 0, stream>>>(pooled, Wlin, blin, out);
}

// Round 11
// 355.575 us; speedup vs baseline: 1.9926x; 1.0973x over previous
//
#include <hip/hip_runtime.h>

#define D 128
#define NLAYERS 5

using short8  = __attribute__((ext_vector_type(8))) short;
using short4v = __attribute__((ext_vector_type(4))) short;
using floatx4 = __attribute__((ext_vector_type(4))) float;
using floatx2 = __attribute__((ext_vector_type(2))) float;

__device__ __forceinline__ unsigned bf16_rne(float x) {
    unsigned u = __float_as_uint(x);
    return (u + 0x7fffu + ((u >> 16) & 1u)) >> 16;
}
__device__ __forceinline__ float bf16_to_f32(short s) {
    return __uint_as_float(((unsigned)(unsigned short)s) << 16);
}

// H is stored as fp8 e4m3 with a fixed x16 scale (power of 2 => scaling is exact).
#define HSCALE 16.0f
#define HSCALE_INV 0.0625f

// ---------------- prepA: W transpose/bf16 + H0 gather (fp8) + fused edge histogram ----------------
__global__ void prepA_kernel(const int* __restrict__ x, const float* __restrict__ emb,
                             const float* __restrict__ Wa, const float* __restrict__ Wb,
                             const int* __restrict__ edst,
                             unsigned char* __restrict__ H0, short* __restrict__ wt,
                             int* __restrict__ deg,
                             int n_nodes, int n_edges) {
    const int gtid = blockIdx.x * 256 + threadIdx.x;
    const int gsz  = gridDim.x * 256;
    for (int g = gtid; g < 2 * NLAYERS * D * D; g += gsz) {
        int mat = g >> 14, idx = g & 16383;
        int n = idx >> 7, k = idx & 127;
        const float* W = (mat & 1) ? (Wb + (size_t)(mat >> 1) * D * D)
                                   : (Wa + (size_t)(mat >> 1) * D * D);
        wt[g] = (short)bf16_rne(W[k * D + n]);
    }
    for (int t = gtid; t < n_nodes * 32; t += gsz) {
        int node = t >> 5, lane = t & 31;
        int s = x[node];
        const float4 v = *reinterpret_cast<const float4*>(emb + (size_t)s * D + lane * 4);
        int w = __builtin_amdgcn_cvt_pk_fp8_f32(v.x * HSCALE, v.y * HSCALE, 0, false);
        w = __builtin_amdgcn_cvt_pk_fp8_f32(v.z * HSCALE, v.w * HSCALE, w, true);
        reinterpret_cast<unsigned int*>(H0)[(size_t)node * 32 + lane] = (unsigned int)w;
    }
    for (int e = gtid; e < n_edges; e += gsz) atomicAdd(&deg[edst[e]], 1);
}

#define SCAN_TILE 1024
__global__ void scan_sums_kernel(const int* __restrict__ deg, int* __restrict__ bsums, int n) {
    __shared__ int red[256];
    int base = blockIdx.x * SCAN_TILE + threadIdx.x * 4;
    int s = 0;
    #pragma unroll
    for (int j = 0; j < 4; j++) {
        int i = base + j;
        if (i < n) s += deg[i];
    }
    red[threadIdx.x] = s;
    __syncthreads();
    for (int off = 128; off > 0; off >>= 1) {
        if (threadIdx.x < off) red[threadIdx.x] += red[threadIdx.x + off];
        __syncthreads();
    }
    if (threadIdx.x == 0) bsums[blockIdx.x] = red[0];
}

__global__ void scan_bsums_kernel(int* __restrict__ bsums, int nblocks) {
    __shared__ int sdata[256];
    int carry = 0;
    for (int base = 0; base < nblocks; base += 256) {
        int i = base + threadIdx.x;
        int v = (i < nblocks) ? bsums[i] : 0;
        sdata[threadIdx.x] = v;
        __syncthreads();
        for (int off = 1; off < 256; off <<= 1) {
            int t = (threadIdx.x >= off) ? sdata[threadIdx.x - off] : 0;
            __syncthreads();
            sdata[threadIdx.x] += t;
            __syncthreads();
        }
        int incl = sdata[threadIdx.x];
        if (i < nblocks) bsums[i] = carry + incl - v;
        carry += sdata[255];
        __syncthreads();
    }
}

__global__ void scan_final_kernel(const int* __restrict__ deg, const int* __restrict__ bsums,
                                  int* __restrict__ offsets, int* __restrict__ cursor, int n) {
    __shared__ int sdata[256];
    int base = blockIdx.x * SCAN_TILE + threadIdx.x * 4;
    int v[4];
    int s = 0;
    #pragma unroll
    for (int j = 0; j < 4; j++) {
        int i = base + j;
        v[j] = (i < n) ? deg[i] : 0;
        s += v[j];
    }
    sdata[threadIdx.x] = s;
    __syncthreads();
    for (int off = 1; off < 256; off <<= 1) {
        int t = (threadIdx.x >= off) ? sdata[threadIdx.x - off] : 0;
        __syncthreads();
        sdata[threadIdx.x] += t;
        __syncthreads();
    }
    int excl = sdata[threadIdx.x] - s + bsums[blockIdx.x];
    #pragma unroll
    for (int j = 0; j < 4; j++) {
        int i = base + j;
        if (i <= n) offsets[i] = excl;
        if (i < n) cursor[i] = excl;
        excl += v[j];
    }
}

__global__ void fill_kernel(const int* __restrict__ esrc, const int* __restrict__ edst,
                            int* __restrict__ cursor, int* __restrict__ csr_src, int n_edges) {
    int e = blockIdx.x * 256 + threadIdx.x;
    if (e >= n_edges) return;
    int pos = atomicAdd(&cursor[edst[e]], 1);
    csr_src[pos] = esrc[e];
}

// aggregate one row (fp8 h_in) into acc[16]; R5's exact edge order and add tree
__device__ __forceinline__ void agg_row(const int* __restrict__ offsets,
                                        const int* __restrict__ csr_src,
                                        const unsigned char* __restrict__ h_in,
                                        int gr, int l8, float* acc) {
    {   // self
        uint4 w = *reinterpret_cast<const uint4*>(h_in + (size_t)gr * D + l8 * 16);
        unsigned int wd[4] = {w.x, w.y, w.z, w.w};
        #pragma unroll
        for (int k = 0; k < 4; k++) {
            floatx2 lo = __builtin_amdgcn_cvt_pk_f32_fp8((int)wd[k], false);
            floatx2 hi = __builtin_amdgcn_cvt_pk_f32_fp8((int)wd[k], true);
            acc[4 * k]     = lo[0]; acc[4 * k + 1] = lo[1];
            acc[4 * k + 2] = hi[0]; acc[4 * k + 3] = hi[1];
        }
    }
    int e   = offsets[gr];
    int end = offsets[gr + 1];
    for (; e + 3 < end; e += 4) {
        int sA = csr_src[e];
        int sB = csr_src[e + 1];
        int sC = csr_src[e + 2];
        int sD = csr_src[e + 3];
        uint4 wA = *reinterpret_cast<const uint4*>(h_in + (size_t)sA * D + l8 * 16);
        uint4 wB = *reinterpret_cast<const uint4*>(h_in + (size_t)sB * D + l8 * 16);
        uint4 wC = *reinterpret_cast<const uint4*>(h_in + (size_t)sC * D + l8 * 16);
        uint4 wD = *reinterpret_cast<const uint4*>(h_in + (size_t)sD * D + l8 * 16);
        unsigned int da[4] = {wA.x, wA.y, wA.z, wA.w};
        unsigned int db[4] = {wB.x, wB.y, wB.z, wB.w};
        unsigned int dc[4] = {wC.x, wC.y, wC.z, wC.w};
        unsigned int dd[4] = {wD.x, wD.y, wD.z, wD.w};
        #pragma unroll
        for (int k = 0; k < 4; k++) {
            floatx2 alo = __builtin_amdgcn_cvt_pk_f32_fp8((int)da[k], false);
            floatx2 ahi = __builtin_amdgcn_cvt_pk_f32_fp8((int)da[k], true);
            floatx2 blo = __builtin_amdgcn_cvt_pk_f32_fp8((int)db[k], false);
            floatx2 bhi = __builtin_amdgcn_cvt_pk_f32_fp8((int)db[k], true);
            floatx2 clo = __builtin_amdgcn_cvt_pk_f32_fp8((int)dc[k], false);
            floatx2 chi = __builtin_amdgcn_cvt_pk_f32_fp8((int)dc[k], true);
            floatx2 dlo = __builtin_amdgcn_cvt_pk_f32_fp8((int)dd[k], false);
            floatx2 dhi = __builtin_amdgcn_cvt_pk_f32_fp8((int)dd[k], true);
            acc[4 * k]     += (alo[0] + blo[0]) + (clo[0] + dlo[0]);
            acc[4 * k + 1] += (alo[1] + blo[1]) + (clo[1] + dlo[1]);
            acc[4 * k + 2] += (ahi[0] + bhi[0]) + (chi[0] + dhi[0]);
            acc[4 * k + 3] += (ahi[1] + bhi[1]) + (chi[1] + dhi[1]);
        }
    }
    for (; e < end; e++) {
        int sA = csr_src[e];
        uint4 wA = *reinterpret_cast<const uint4*>(h_in + (size_t)sA * D + l8 * 16);
        unsigned int da[4] = {wA.x, wA.y, wA.z, wA.w};
        #pragma unroll
        for (int k = 0; k < 4; k++) {
            floatx2 alo = __builtin_amdgcn_cvt_pk_f32_fp8((int)da[k], false);
            floatx2 ahi = __builtin_amdgcn_cvt_pk_f32_fp8((int)da[k], true);
            acc[4 * k]     += alo[0];
            acc[4 * k + 1] += alo[1];
            acc[4 * k + 2] += ahi[0];
            acc[4 * k + 3] += ahi[1];
        }
    }
}

// ---------------- fused layer, 128 rows/block, 1024 threads (16 waves) ----------------
// R10 gave: 128-row amortization (weight staging 50MB/layer) -> layer 64->44.5us, but each
// thread aggregated 2 rows serially at only 16 waves/CU. This round keeps the amortization
// and restores agg parallelism: 1024 threads -> ONE row per 8-lane group (R5 chain) and
// 2 blocks/CU x 16 waves = 32 waves/CU issuing gathers (max thread occupancy).
// GEMM: 8 row-stripes (wr=0..7, 16 rows each) x 2 col-halves (wc); acc[4]/wave.
// LDS: zsh 32KB + one weight buffer 32KB = 64KB -> 2 blocks/CU. wb overwrites wa between
// GEMMs (hides under bias/relu). Last layer: h_out null (pool-only).
// zsh 16B chunks XOR-swizzled: chunk c of row r at (c ^ (r&15)).
// __launch_bounds__(1024, 8): cap VGPR at 64 so 2 blocks/CU is achievable (R5's agg = 40 VGPR).
__global__ __launch_bounds__(1024, 8) void layer_kernel(
        const int* __restrict__ offsets, const int* __restrict__ csr_src,
        const unsigned char* __restrict__ h_in, const short* __restrict__ wta,
        const short* __restrict__ wtb, const float* __restrict__ ba,
        const float* __restrict__ bb, unsigned char* __restrict__ h_out,
        float* __restrict__ pooled_accum, int n_rows) {
    __shared__ __align__(16) short zsh[128 * 128];    // 32 KB: z tile, then t tile, then pool scratch
    __shared__ __align__(16) short wsh[128 * 128];    // 32 KB: wa for GEMM1, then wb for GEMM2

    const int tid  = threadIdx.x;
    const int row0 = blockIdx.x * 128;

    #pragma unroll
    for (int i = 0; i < 2; i++) {
        int g = i * 1024 + tid;
        int n = g >> 4, c = g & 15;
        int off = (n * 16 + (c ^ (n & 15))) * 8;
        *reinterpret_cast<short8*>(&wsh[off]) =
            *reinterpret_cast<const short8*>(wta + n * D + c * 8);
    }

    {
        const int r  = tid >> 3;         // 0..127: one row per 8-lane group
        const int l8 = tid & 7;
        const int gr = row0 + r;
        float acc[16];
        if (gr < n_rows) {
            agg_row(offsets, csr_src, h_in, gr, l8, acc);
        } else {
            #pragma unroll
            for (int j = 0; j < 16; j++) acc[j] = 0.f;
        }
        short8 o0, o1;
        #pragma unroll
        for (int j = 0; j < 8; j++) {
            o0[j] = (short)bf16_rne(acc[j] * HSCALE_INV);
            o1[j] = (short)bf16_rne(acc[8 + j] * HSCALE_INV);
        }
        const int c0i = 2 * l8, c1i = 2 * l8 + 1;
        *reinterpret_cast<short8*>(&zsh[(r * 16 + (c0i ^ (r & 15))) * 8]) = o0;
        *reinterpret_cast<short8*>(&zsh[(r * 16 + (c1i ^ (r & 15))) * 8]) = o1;
    }
    __syncthreads();

    const int lane = tid & 63;
    const int wave = tid >> 6;           // 0..15
    const int wr   = wave >> 1;          // 0..7: 16-row stripe
    const int wc   = wave & 1;           // 0..1: 64-col half
    const int lm   = lane & 15;
    const int quad = lane >> 4;

    floatx4 acc1[4];
    #pragma unroll
    for (int cs = 0; cs < 4; cs++) acc1[cs] = floatx4{0.f, 0.f, 0.f, 0.f};
    {
        const int r = wr * 16 + lm;
        #pragma unroll
        for (int ks = 0; ks < 4; ks++) {
            const int c = ks * 4 + quad;
            short8 av = *reinterpret_cast<const short8*>(&zsh[(r * 16 + (c ^ (r & 15))) * 8]);
            #pragma unroll
            for (int cs = 0; cs < 4; cs++) {
                int nn = wc * 64 + cs * 16 + lm;
                short8 bv = *reinterpret_cast<const short8*>(&wsh[(nn * 16 + (c ^ (nn & 15))) * 8]);
                acc1[cs] = __builtin_amdgcn_mfma_f32_16x16x32_bf16(av, bv, acc1[cs], 0, 0, 0);
            }
        }
    }
    __syncthreads();   // all wa + z1 reads done; wsh and zsh may be overwritten

    // load wb over wa (L2-hot; hides under the bias/relu VALU work below)
    #pragma unroll
    for (int i = 0; i < 2; i++) {
        int g = i * 1024 + tid;
        int n = g >> 4, c = g & 15;
        int off = (n * 16 + (c ^ (n & 15))) * 8;
        *reinterpret_cast<short8*>(&wsh[off]) =
            *reinterpret_cast<const short8*>(wtb + n * D + c * 8);
    }

    #pragma unroll
    for (int cs = 0; cs < 4; cs++) {
        int col = wc * 64 + cs * 16 + lm;
        float bva = ba[col];
        int cj = col >> 3, ci = col & 7;
        #pragma unroll
        for (int reg = 0; reg < 4; reg++) {
            int r = wr * 16 + quad * 4 + reg;
            float v = fmaxf(acc1[cs][reg] + bva, 0.f);
            zsh[(r * 16 + (cj ^ (r & 15))) * 8 + ci] = (short)bf16_rne(v);
        }
    }
    __syncthreads();

    floatx4 acc2[4];
    #pragma unroll
    for (int cs = 0; cs < 4; cs++) acc2[cs] = floatx4{0.f, 0.f, 0.f, 0.f};
    {
        const int r = wr * 16 + lm;
        #pragma unroll
        for (int ks = 0; ks < 4; ks++) {
            const int c = ks * 4 + quad;
            short8 av = *reinterpret_cast<const short8*>(&zsh[(r * 16 + (c ^ (r & 15))) * 8]);
            #pragma unroll
            for (int cs = 0; cs < 4; cs++) {
                int nn = wc * 64 + cs * 16 + lm;
                short8 bv = *reinterpret_cast<const short8*>(&wsh[(nn * 16 + (c ^ (nn & 15))) * 8]);
                acc2[cs] = __builtin_amdgcn_mfma_f32_16x16x32_bf16(av, bv, acc2[cs], 0, 0, 0);
            }
        }
    }

    float psum[4];   // per-thread, per-cs column partial (only used on last layer)
    #pragma unroll
    for (int cs = 0; cs < 4; cs++) {
        int col = wc * 64 + cs * 16 + lm;
        float bvb = bb[col];
        float s = 0.f;
        #pragma unroll
        for (int reg = 0; reg < 4; reg++) {
            int r = row0 + wr * 16 + quad * 4 + reg;
            if (r < n_rows) {
                float v = fmaxf(acc2[cs][reg] + bvb, 0.f);
                if (h_out != nullptr) {
                    float sv = v * HSCALE;
                    int pw = __builtin_amdgcn_cvt_pk_fp8_f32(sv, sv, 0, false);
                    h_out[(size_t)r * D + col] = (unsigned char)(pw & 0xff);
                }
                s += v;   // pool the f32 value (last layer stores nothing)
            }
        }
        psum[cs] = s;
    }

    if (pooled_accum != nullptr) {
        __syncthreads();                 // all gemm2 zsh reads done; reuse zsh as f32 scratch
        float* part = (float*)zsh;       // [32][128] floats = 16KB
        #pragma unroll
        for (int cs = 0; cs < 4; cs++)
            part[(wr * 4 + quad) * 128 + wc * 64 + cs * 16 + lm] = psum[cs];
        __syncthreads();
        if (tid < 128) {
            float s = 0.f;
            #pragma unroll
            for (int g = 0; g < 32; g++) s += part[g * 128 + tid];
            atomicAdd(&pooled_accum[tid], s);
        }
    }
}

// ---------------- final linear (fp32 exact) ----------------
__global__ void final_kernel(const float* __restrict__ pooled, const float* __restrict__ Wlin,
                             const float* __restrict__ blin, float* __restrict__ out) {
    const int j = threadIdx.x;
    __shared__ float p[D];
    p[j] = pooled[j];
    __syncthreads();
    float s = blin[j];
    #pragma unroll 8
    for (int k = 0; k < D; k++) s += p[k] * Wlin[k * D + j];
    out[j] = s;
}

extern "C" void kernel_launch(void* const* d_in, const int* in_sizes, int n_in,
                              void* d_out, int out_size, void* d_ws, size_t ws_size,
                              hipStream_t stream) {
    const int*   x    = (const int*)d_in[0];
    const int*   ei   = (const int*)d_in[1];
    const float* emb  = (const float*)d_in[2];
    const float* Wa   = (const float*)d_in[3];
    const float* ba   = (const float*)d_in[4];
    const float* Wb   = (const float*)d_in[5];
    const float* bb   = (const float*)d_in[6];
    const float* Wlin = (const float*)d_in[7];
    const float* blin = (const float*)d_in[8];
    float* out = (float*)d_out;

    const int N = in_sizes[0];
    const int E = in_sizes[1] / 2;
    const int* esrc = ei;
    const int* edst = ei + E;

    // workspace: H0 | H1 (fp8, N*128 bytes each) | pooled | deg | offsets | cursor | bsums | csr_src | wt
    unsigned char* H0 = (unsigned char*)d_ws;           // N*128 bytes
    unsigned char* H1 = H0 + (size_t)N * D;             // N*128 bytes
    float* pooled = (float*)(H1 + (size_t)N * D);       // 128
    int* deg     = (int*)(pooled + 128);                // N
    int* offsets = deg + N;                             // N+1
    int* cursor  = offsets + (N + 1);                   // N
    int* bsums   = cursor + N;                          // 4096
    int* csr_src = bsums + 4096;                        // E
    uintptr_t wt_addr = ((uintptr_t)(csr_src + E) + 15) & ~(uintptr_t)15;
    short* wt = (short*)wt_addr;                        // [10][128][128] bf16

    const int scan_blocks = (N + 1 + SCAN_TILE - 1) / SCAN_TILE;

    // zero pooled[128] + deg[N] in one contiguous memset (graph-capture-safe)
    hipMemsetAsync(pooled, 0, (size_t)(128 + N) * sizeof(int), stream);

    prepA_kernel<<<1024, 256, 0, stream>>>(x, emb, Wa, Wb, edst, H0, wt, deg, N, E);
    scan_sums_kernel<<<scan_blocks, 256, 0, stream>>>(deg, bsums, N);
    scan_bsums_kernel<<<1, 256, 0, stream>>>(bsums, scan_blocks);
    scan_final_kernel<<<scan_blocks, 256, 0, stream>>>(deg, bsums, offsets, cursor, N);
    fill_kernel<<<(E + 255) / 256, 256, 0, stream>>>(esrc, edst, cursor, csr_src, E);

    const int layer_blocks = (N + 127) / 128;
    unsigned char* hin = H0; unsigned char* hout = H1;
    for (int l = 0; l < NLAYERS; l++) {
        const bool last = (l == NLAYERS - 1);
        float* pacc = last ? pooled : nullptr;
        unsigned char* hdst = last ? nullptr : hout;   // last layer: output only feeds the pool
        layer_kernel<<<layer_blocks, 1024, 0, stream>>>(
            offsets, csr_src, hin,
            wt + (size_t)(2 * l) * D * D, wt + (size_t)(2 * l + 1) * D * D,
            ba + (size_t)l * D, bb + (size_t)l * D, hdst, pacc, N);
        unsigned char* tmp = hin; hin = hout; hout = tmp;
    }

    final_kernel<<<1, 128, 0, stream>>>(pooled, Wlin, blin, out);
}